// Round 7
// baseline (250.001 us; speedup 1.0000x reference)
//
#include <hip/hip_runtime.h>

#define CH 256
#define HH 56
#define WW 56
#define HWSZ 3136
#define WQ_ELEMS (CH*CH*9)      // 589824

#define XROW 2048               // shorts: 64 iw * 32 ic
#define XBUF (6*XROW)           // 12288 shorts per X buffer
#define WBUF 24576              // shorts: 3 kw * 256 oc * 32 ic per W buffer

typedef short short8 __attribute__((ext_vector_type(8)));
typedef float f32x4 __attribute__((ext_vector_type(4)));
typedef __attribute__((address_space(3))) unsigned short as3_ushort;
typedef __attribute__((address_space(1))) const unsigned short as1_ushort;

__device__ __forceinline__ unsigned short f2bf(float f) {
  unsigned u = __builtin_bit_cast(unsigned, f);
  u += 0x7FFFu + ((u >> 16) & 1u);   // round-to-nearest-even
  return (unsigned short)(u >> 16);
}

// ---------------- kernel 1: max(|w|), float4 ----------------
__global__ void absmax_kernel(const float4* __restrict__ w, unsigned* __restrict__ out) {
  int tid = blockIdx.x * 256 + threadIdx.x;
  float4 v = w[tid];
  float m = fmaxf(fmaxf(fabsf(v.x), fabsf(v.y)), fmaxf(fabsf(v.z), fabsf(v.w)));
  #pragma unroll
  for (int o = 32; o; o >>= 1) m = fmaxf(m, __shfl_xor(m, o, 64));
  if ((threadIdx.x & 63) == 0) atomicMax(out, __builtin_bit_cast(unsigned, m));
}

// ---------------- kernel 2: quantize -> bf16 (same verified layout as R6) ----------------
// region (tap*8+t) of 8192 shorts; within: och*4096 + m8*512 + l15*32 + kgp*8 + e,
// kgp = kg ^ ((l15>>2)&3).
__global__ void quant_kernel(const float* __restrict__ w, const float* __restrict__ Wp,
                             const float* __restrict__ Wn, const unsigned* __restrict__ mx,
                             unsigned short* __restrict__ wq) {
  int o = blockIdx.x * 256 + threadIdx.x;
  int e   = o & 7;
  int kgp = (o >> 3) & 3;
  int l15 = (o >> 5) & 15;
  int m   = (o >> 9) & 7;
  int och = (o >> 12) & 1;
  int region = o >> 13;            // tap*8 + t
  int tap = region >> 3;
  int t   = region & 7;
  int kg  = kgp ^ ((l15 >> 2) & 3);
  int oc  = och * 128 + m * 16 + l15;
  int ic  = t * 32 + kg * 8 + e;
  float mv  = __builtin_bit_cast(float, *mx);
  float thr = 0.05f * mv;
  float v = w[(oc * CH + ic) * 9 + tap];
  float q = 0.f;
  if (mv > 0.f) {
    if (v > thr) q = Wp[0];
    else if (v < -thr) q = -Wn[0];
  }
  wq[o] = f2bf(q);
}

// ---------------- kernel 3: conv, 16 waves (4/SIMD), counted-vmcnt pipeline ----------------
__global__ __launch_bounds__(1024, 1)
void conv_kernel(const float* __restrict__ x, const unsigned short* __restrict__ wq,
                 const float* __restrict__ bias, float* __restrict__ out) {
  extern __shared__ __align__(16) unsigned short lds[];
  unsigned short* Wl = lds;              // 2 * WBUF shorts (96 KB)
  unsigned short* Xl = lds + 2 * WBUF;   // 2 * XBUF shorts (48 KB)

  const int tid  = threadIdx.x;
  const int lane = tid & 63;
  const int l15  = lane & 15;
  const int kg   = lane >> 4;
  const int wid  = tid >> 6;       // 0..15
  const int q    = wid & 3;        // oc quarter (64 oc)
  const int wr   = wid >> 2;       // output row 0..3
  const int n    = blockIdx.x;
  const int h0   = blockIdx.y * 4;

  f32x4 acc[4][4];
  #pragma unroll
  for (int m = 0; m < 4; ++m)
    #pragma unroll
    for (int nc = 0; nc < 4; ++nc) acc[m][nc] = (f32x4)0.f;

  // ---- X staging geometry: chunk c = (r, iw, slot8); c = tid, and tid+1024 (tid<512) ----
  int goff[2], loff[2];
  bool ok[2];
  #pragma unroll
  for (int k = 0; k < 2; ++k) {
    int c    = tid + k * 1024;     // < 1536 for valid threads
    int slot = c & 3;
    int qq   = c >> 2;
    int iw   = qq & 63;
    int r    = (qq >> 6) & 7;      // 0..5
    int hx = h0 + r - 1;
    int xw = iw - 1;
    ok[k] = ((unsigned)hx < (unsigned)HH) && ((unsigned)xw < (unsigned)WW);
    goff[k] = slot * 8 * HWSZ + (ok[k] ? (hx * WW + xw) : 0);
    loff[k] = r * XROW + iw * 32 + ((slot ^ ((iw >> 1) & 3)) * 8);
  }
  const float* xbase = x + (long)n * CH * HWSZ;

  // ---- B-read offsets (zero-conflict swizzle, measured in R4) ----
  int boff[12];
  #pragma unroll
  for (int nc = 0; nc < 4; ++nc)
    #pragma unroll
    for (int kw = 0; kw < 3; ++kw) {
      int iw = nc * 16 + l15 + kw;
      if (iw > 63) iw = 63;        // feeds only discarded w >= 56
      boff[nc * 3 + kw] = iw * 32 + ((kg ^ ((iw >> 1) & 3)) * 8);
    }

  // ---- A-read offset (matches quant layout); quarter q -> och*4096 + mhalf*2048 ----
  const int aoff = q * 2048 + l15 * 32 + ((kg ^ ((l15 >> 2) & 3)) * 8);

  // ---- W-stage: exactly 3 gload_lds per wave per step (48 x 1KB total) ----
  auto stageW = [&](int s) {
    const int tt = s / 3, khh = s - tt * 3;
    const int base = (s & 1) * WBUF;
    #pragma unroll
    for (int i = 0; i < 3; ++i) {
      const int g   = i * 16 + wid;      // 0..47
      const int kw  = g >> 4;
      const int sub = g & 15;
      const unsigned short* src = wq + ((khh * 3 + kw) * 8 + tt) * 8192 + sub * 512 + lane * 8;
      unsigned short* dst = Wl + base + kw * 8192 + sub * 512;
      __builtin_amdgcn_global_load_lds((as1_ushort*)src, (as3_ushort*)dst, 16, 0, 0);
    }
  };

  float xr0[8], xr1[8];
  // waves 0-7 issue 16 vm ops, waves 8-15 issue 8 (wave-uniform classes)
  auto loadX = [&](int t1) {
    const int ic0 = t1 * 32;
    #pragma unroll
    for (int j = 0; j < 8; ++j) xr0[j] = xbase[goff[0] + (ic0 + j) * HWSZ];
    if (tid < 512) {
      #pragma unroll
      for (int j = 0; j < 8; ++j) xr1[j] = xbase[goff[1] + (ic0 + j) * HWSZ];
    }
  };
  auto writeX = [&](int buf) {
    short8 p;
    #pragma unroll
    for (int j = 0; j < 8; ++j) p[j] = ok[0] ? (short)f2bf(xr0[j]) : (short)0;
    *(short8*)&Xl[buf + loff[0]] = p;
    if (tid < 512) {
      short8 p2;
      #pragma unroll
      for (int j = 0; j < 8; ++j) p2[j] = ok[1] ? (short)f2bf(xr1[j]) : (short)0;
      *(short8*)&Xl[buf + loff[1]] = p2;
    }
  };

  auto mfmaStep = [&](int s, int kh, int xcur) {
    const int wb  = (s & 1) * WBUF;
    const int rxo = xcur + (wr + kh) * XROW;
    __builtin_amdgcn_s_setprio(1);
    #pragma unroll
    for (int kw = 0; kw < 3; ++kw) {
      const unsigned short* ap = Wl + wb + kw * 8192 + aoff;
      short8 a[4];
      #pragma unroll
      for (int m = 0; m < 4; ++m) a[m] = *(const short8*)(ap + m * 512);
      short8 b[4];
      #pragma unroll
      for (int nc = 0; nc < 4; ++nc) b[nc] = *(const short8*)&Xl[rxo + boff[nc * 3 + kw]];
      #pragma unroll
      for (int m = 0; m < 4; ++m)
        #pragma unroll
        for (int nc = 0; nc < 4; ++nc)
          acc[m][nc] = __builtin_amdgcn_mfma_f32_16x16x32_bf16(a[m], b[nc], acc[m][nc], 0, 0, 0);
    }
    __builtin_amdgcn_s_setprio(0);
  };

  // ---- prologue: X(0) + W(0); drain X, write X; W(0) drained at t=0 start ----
  loadX(0);
  stageW(0);
  asm volatile("s_waitcnt vmcnt(3)" ::: "memory");   // X done, W(0) in flight
  writeX(0);
  asm volatile("s_waitcnt lgkmcnt(0)" ::: "memory");
  __builtin_amdgcn_s_barrier();
  __builtin_amdgcn_sched_barrier(0);

  for (int t = 0; t < 8; ++t) {
    const int xcur = (t & 1) * XBUF;
    const int xnxt = XBUF - xcur;
    const int s0 = t * 3;

    // ---- kh = 0 ----
    asm volatile("s_waitcnt vmcnt(0)" ::: "memory");   // W(s0) landed (full cluster + barrier of cover)
    __builtin_amdgcn_sched_barrier(0);
    stageW(s0 + 1);
    mfmaStep(s0, 0, xcur);
    __builtin_amdgcn_s_barrier();
    __builtin_amdgcn_sched_barrier(0);

    // ---- kh = 1 ----
    asm volatile("s_waitcnt vmcnt(0)" ::: "memory");   // W(s0+1)
    __builtin_amdgcn_sched_barrier(0);
    stageW(s0 + 2);
    if (t < 7) loadX(t + 1);                           // X newest; 2 clusters of cover
    mfmaStep(s0 + 1, 1, xcur);
    __builtin_amdgcn_s_barrier();
    __builtin_amdgcn_sched_barrier(0);

    // ---- kh = 2 ----
    if (t < 7) { asm volatile("s_waitcnt vmcnt(8)" ::: "memory"); }   // drain W(s0+2), keep X
    else       { asm volatile("s_waitcnt vmcnt(0)" ::: "memory"); }
    __builtin_amdgcn_sched_barrier(0);
    if (t < 7) stageW(s0 + 3);
    mfmaStep(s0 + 2, 2, xcur);
    if (t < 7) {
      asm volatile("s_waitcnt vmcnt(3)" ::: "memory");  // X done, W(s0+3) stays in flight
      writeX(xnxt);
    }
    asm volatile("s_waitcnt lgkmcnt(0)" ::: "memory");
    __builtin_amdgcn_s_barrier();
    __builtin_amdgcn_sched_barrier(0);
  }

  // ---- epilogue: D col = l15 (w), row = kg*4 + j (oc) ----
  const int h = h0 + wr;
  #pragma unroll
  for (int m = 0; m < 4; ++m) {
    const int ocb = q * 64 + m * 16 + kg * 4;
    #pragma unroll
    for (int nc = 0; nc < 4; ++nc) {
      const int w = nc * 16 + l15;
      if (w < WW) {
        float* op = out + ((long)(n * CH + ocb) * HH + h) * WW + w;
        #pragma unroll
        for (int j = 0; j < 4; ++j)
          op[(long)j * HWSZ] = acc[m][nc][j] + bias[ocb + j];
      }
    }
  }
}

extern "C" void kernel_launch(void* const* d_in, const int* in_sizes, int n_in,
                              void* d_out, int out_size, void* d_ws, size_t ws_size,
                              hipStream_t stream) {
  const float* x      = (const float*)d_in[0];
  const float* weight = (const float*)d_in[1];
  const float* bias   = (const float*)d_in[2];
  const float* Wp     = (const float*)d_in[3];
  const float* Wn     = (const float*)d_in[4];
  float* out          = (float*)d_out;

  unsigned* mx        = (unsigned*)d_ws;
  unsigned short* wqp = (unsigned short*)((char*)d_ws + 64);

  static const int LDS_BYTES = 2 * (WBUF + XBUF) * 2;   // 147456
  hipFuncSetAttribute((const void*)conv_kernel,
                      hipFuncAttributeMaxDynamicSharedMemorySize, LDS_BYTES);

  hipMemsetAsync(d_ws, 0, 64, stream);
  absmax_kernel<<<WQ_ELEMS / 4 / 256, 256, 0, stream>>>((const float4*)weight, mx);
  quant_kernel<<<WQ_ELEMS / 256, 256, 0, stream>>>(weight, Wp, Wn, mx, wqp);
  conv_kernel<<<dim3(32, HH / 4), 1024, LDS_BYTES, stream>>>(x, wqp, bias, out);
}